// Round 3
// baseline (354.266 us; speedup 1.0000x reference)
//
#include <hip/hip_runtime.h>
#include <stdint.h>

// GeometricPositionalFingerprinter on MI355X — round 3: 4 lanes/anchor.
//
// Phase 1: 4 lanes per anchor, 16 dims (4x float4) per lane. Per (v,k) load
//   instruction each anchor's 4 lanes cover exactly one 64B line -> perfect
//   coalescing (16 anchors x 1 line = 1KB/instr, 100% used). Only the 15
//   Gram inner products are accumulated (f64; products of f32 are exact).
//   2-step shfl_xor butterfly (4 lanes) -> 3x fewer ds_swizzle ops than the
//   round-2 8-lane variant (the LDS pipe was the dominant removable cost).
// Phase 2: one thread per anchor (after LDS handoff + barrier):
//   dist^2(i,j) = ip_ii + ip_jj - 2 ip_ij
//   |v_i - c|^2 = ip_ii - 2/5 * rowsum_i + 1/25 * totsum
//   V^2 = det(Gram(v_i - v_0)) / 576  (closed-form 4x4 cofactor det)
// All sensitive math in f64: Cantor digits amplify seed error by 3^k; the
// f64 pipeline matches the np reference to the last digit (absmax 2^-8).

#define THREADS 256
#define ANCH_PER_BLOCK 256

__global__ __launch_bounds__(THREADS) void fingerprint_kernel(
    const float* __restrict__ vertices,
    const void* __restrict__ ids_raw,
    float* __restrict__ out,
    int n)
{
    // stats[anchor_local][0..14] = upper-triangular inner products
    // row stride 17 doubles -> phase-2 reads are 2-way bank aliased (free)
    __shared__ double stats[ANCH_PER_BLOCK][17];

    const int tid  = threadIdx.x;
    const int wave = tid >> 6;          // 0..3
    const int lane = tid & 63;
    const int g    = lane >> 2;         // anchor within 16-anchor tile (0..15)
    const int r    = lane & 3;          // dim-chunk lane (4x float4 each)
    const int blockBase = blockIdx.x * ANCH_PER_BLOCK;

    // ---------------- Phase 1: 15 inner products per anchor ----------------
    #pragma unroll 1
    for (int it = 0; it < 4; ++it) {            // 16 anchors/tile * 4 = 64/wave
        const int alocal = wave * 64 + it * 16 + g;
        int a = blockBase + alocal;
        int aload = (a < n) ? a : (n - 1);
        const float* vb = vertices + (size_t)aload * 320;

        double ip[15];
        #pragma unroll
        for (int p = 0; p < 15; ++p) ip[p] = 0.0;

        #pragma unroll
        for (int k = 0; k < 4; ++k) {
            // lane r loads float4 index k*4+r of each vertex:
            // per (v,k) instruction the 4 lanes of an anchor span one 64B line
            float xv[5][4];
            #pragma unroll
            for (int v = 0; v < 5; ++v) {
                float4 t = *(const float4*)(vb + v * 64 + k * 16 + r * 4);
                xv[v][0] = t.x; xv[v][1] = t.y; xv[v][2] = t.z; xv[v][3] = t.w;
            }
            #pragma unroll
            for (int c = 0; c < 4; ++c) {
                double x[5];
                #pragma unroll
                for (int v = 0; v < 5; ++v) x[v] = (double)xv[v][c];
                int p = 0;
                #pragma unroll
                for (int v = 0; v < 5; ++v)
                    #pragma unroll
                    for (int w = v; w < 5; ++w) {
                        ip[p] = fma(x[v], x[w], ip[p]);
                        ++p;
                    }
            }
        }

        // 2-step butterfly over the 4-lane group
        #pragma unroll
        for (int p = 0; p < 15; ++p) {
            ip[p] += __shfl_xor(ip[p], 1);
            ip[p] += __shfl_xor(ip[p], 2);
        }

        // all 4 lanes hold all 15 sums; spread the stat writes
        stats[alocal][r]     = ip[r];
        stats[alocal][4 + r] = ip[4 + r];
        stats[alocal][8 + r] = ip[8 + r];
        if (r < 3) stats[alocal][12 + r] = ip[12 + r];
    }

    __syncthreads();

    // ---------------- Phase 2: per-anchor tail ----------------
    const int a = blockBase + tid;
    if (a >= n) return;

    double ip[15];
    #pragma unroll
    for (int p = 0; p < 15; ++p) ip[p] = stats[tid][p];

    // ip index lookup: linear upper-triangular order
    const int IP[5][5] = {
        { 0, 1, 2, 3, 4},
        { 1, 5, 6, 7, 8},
        { 2, 6, 9,10,11},
        { 3, 7,10,12,13},
        { 4, 8,11,13,14}};

    // pairwise squared distances
    double dsq[5][5];
    #pragma unroll
    for (int i = 0; i < 5; ++i) {
        dsq[i][i] = 0.0;
        #pragma unroll
        for (int j = i + 1; j < 5; ++j) {
            double d = ip[IP[i][i]] + ip[IP[j][j]] - 2.0 * ip[IP[i][j]];
            dsq[i][j] = d; dsq[j][i] = d;
        }
    }

    // edge stats over 10 unique edges (unbiased std)
    double esum = 0.0, e[10];
    {
        int p = 0;
        #pragma unroll
        for (int i = 0; i < 5; ++i)
            #pragma unroll
            for (int j = i + 1; j < 5; ++j) {
                e[p] = sqrt(dsq[i][j]); esum += e[p]; ++p;
            }
    }
    double emean = esum * 0.1;
    double evar = 0.0;
    #pragma unroll
    for (int p = 0; p < 10; ++p) { double d = e[p] - emean; evar += d * d; }
    double estd = sqrt(evar / 9.0);

    // spread: std of distances to centroid (unbiased)
    double rowsum[5], tot = 0.0;
    #pragma unroll
    for (int i = 0; i < 5; ++i) {
        double s = 0.0;
        #pragma unroll
        for (int w = 0; w < 5; ++w) s += ip[IP[i][w]];
        rowsum[i] = s; tot += s;
    }
    double c2 = tot * 0.04;             // |centroid|^2 = tot/25
    double dsum = 0.0, dd[5];
    #pragma unroll
    for (int i = 0; i < 5; ++i) {
        double s2 = ip[IP[i][i]] - 0.4 * rowsum[i] + c2;   // |v_i - c|^2
        dd[i] = sqrt(fmax(s2, 0.0)); dsum += dd[i];
    }
    double dmean = dsum * 0.2;
    double svar = 0.0;
    #pragma unroll
    for (int i = 0; i < 5; ++i) { double d = dd[i] - dmean; svar += d * d; }
    double spread = sqrt(svar * 0.25);

    // 4-simplex volume via Gram determinant of edge vectors from vertex 0:
    // G[i][j] = (d0i^2 + d0j^2 - dij^2)/2, i,j in 1..4; V^2 = det(G)/576
    double G[4][4];
    #pragma unroll
    for (int i = 0; i < 4; ++i)
        #pragma unroll
        for (int j = 0; j < 4; ++j)
            G[i][j] = 0.5 * (dsq[0][i + 1] + dsq[0][j + 1] - dsq[i + 1][j + 1]);

    double m01 = G[2][2] * G[3][3] - G[2][3] * G[3][2];
    double m02 = G[2][1] * G[3][3] - G[2][3] * G[3][1];
    double m03 = G[2][1] * G[3][2] - G[2][2] * G[3][1];
    double m04 = G[2][0] * G[3][3] - G[2][3] * G[3][0];
    double m05 = G[2][0] * G[3][2] - G[2][2] * G[3][0];
    double m06 = G[2][0] * G[3][1] - G[2][1] * G[3][0];
    double det =
        G[0][0] * (G[1][1] * m01 - G[1][2] * m02 + G[1][3] * m03)
      - G[0][1] * (G[1][0] * m01 - G[1][2] * m04 + G[1][3] * m05)
      + G[0][2] * (G[1][0] * m02 - G[1][1] * m04 + G[1][3] * m06)
      - G[0][3] * (G[1][0] * m03 - G[1][1] * m05 + G[1][2] * m06);

    double volume = sqrt(fmax(det / 576.0, 0.0));

    double vn = 1.0 / (1.0 + exp(-10.0 * volume));
    double er = 1.0 / (1.0 + exp(-(estd / (emean + 1e-6))));
    double sn = 1.0 / (1.0 + exp(-spread));
    double seed = 0.4 * vn + 0.3 * er + 0.3 * sn;

    // anchor id hash: probe whether ids are int64 (jax x64) or int32 layout
    const int* ai32 = (const int*)ids_raw;
    long long idv;
    if (ai32[1] == 0) {           // int64 little-endian: high word of id0
        idv = ((const long long*)ids_raw)[a];
    } else {
        idv = (long long)ai32[a];
    }
    long long h = (idv * 2654435761LL) % 1000000LL;
    double idc = (double)h / 1000000.0;

    seed = 0.1 * seed + 0.9 * idc;
    seed = fmin(fmax(seed, 1e-6), 1.0 - 1e-6);

    // Cantor digit extraction
    double x = seed, cant = 0.0, factor = 0.5;
    #pragma unroll
    for (int itc = 0; itc < 8; ++itc) {
        double xs = x * 3.0;
        int dg = (int)xs;           // trunc, xs in [0,3)
        x = xs - (double)dg;
        cant += (dg == 2) ? factor : 0.0;
        factor *= 0.5;
    }
    out[a] = (float)fmin(fmax(cant, 0.0), 1.0);
}

extern "C" void kernel_launch(void* const* d_in, const int* in_sizes, int n_in,
                              void* d_out, int out_size, void* d_ws, size_t ws_size,
                              hipStream_t stream) {
    const float* vertices = (const float*)d_in[0];
    const void*  ids      = d_in[1];
    float* out = (float*)d_out;
    int n = in_sizes[1];            // anchor count (element count of anchor_ids)
    int grid = (n + ANCH_PER_BLOCK - 1) / ANCH_PER_BLOCK;
    fingerprint_kernel<<<grid, THREADS, 0, stream>>>(vertices, ids, out, n);
}